// Round 1
// baseline (520.851 us; speedup 1.0000x reference)
//
#include <hip/hip_runtime.h>

#define N_NODES 8000
#define FEAT 64
#define HID 128
#define LOOKBACK 12
#define CAP 64

// ---------------- adjacency pattern extraction ----------------
__global__ __launch_bounds__(256)
void build_adj_kernel(const float* __restrict__ adj, int* __restrict__ cnt,
                      int* __restrict__ lists) {
    long q = (long)blockIdx.x * 256 + threadIdx.x;           // float4 index
    const long NQ = (long)N_NODES * N_NODES / 4;
    if (q >= NQ) return;
    int i  = (int)(q / (N_NODES / 4));
    int j0 = (int)(q % (N_NODES / 4)) * 4;
    float4 w = *reinterpret_cast<const float4*>(adj + (long)i * N_NODES + j0);
    float wv[4] = {w.x, w.y, w.z, w.w};
    #pragma unroll
    for (int c = 0; c < 4; ++c) {
        if (wv[c] != 0.0f) {
            int j = j0 + c;
            int p = atomicAdd(&cnt[j], 1);
            if (p < CAP) lists[(long)j * CAP + p] = i;       // edge i -> j
        }
    }
}

// sort each target's source list (determinism across replays) + deg
__global__ __launch_bounds__(256)
void sort_deg_kernel(int* __restrict__ cnt, int* __restrict__ lists,
                     float* __restrict__ degf) {
    int j = blockIdx.x * 256 + threadIdx.x;
    if (j >= N_NODES) return;
    int m = cnt[j];
    if (m > CAP) m = CAP;
    cnt[j] = m;
    int* l = lists + (long)j * CAP;
    for (int a = 1; a < m; ++a) {
        int v = l[a];
        int b = a - 1;
        while (b >= 0 && l[b] > v) { l[b + 1] = l[b]; --b; }
        l[b + 1] = v;
    }
    degf[j] = (float)(m > 0 ? m : 1);
}

// stack [Wl1;Wr1] -> Ws1 [128][128], [Wl2;Wr2] -> Ws2 [256][64]
__global__ __launch_bounds__(256)
void prep_weights_kernel(const float* __restrict__ Wl1, const float* __restrict__ Wr1,
                         const float* __restrict__ Wl2, const float* __restrict__ Wr2,
                         float* __restrict__ Ws1, float* __restrict__ Ws2) {
    int g = blockIdx.x * 256 + threadIdx.x;
    if (g < 128 * 128) {
        int k = g / 128, j = g % 128;
        Ws1[g] = (k < 64) ? Wl1[k * 128 + j] : Wr1[(k - 64) * 128 + j];
    } else if (g < 128 * 128 + 256 * 64) {
        int g2 = g - 128 * 128;
        int k = g2 / 64, j = g2 % 64;
        Ws2[g2] = (k < 128) ? Wl2[k * 64 + j] : Wr2[(k - 128) * 64 + j];
    }
}

// ---------------- init encoder: x[L,N,F] -> x0[N,F] ----------------
__global__ __launch_bounds__(256)
void init_enc_kernel(const float* __restrict__ x, const float* __restrict__ We1,
                     const float* __restrict__ be1, const float* __restrict__ We2,
                     const float* __restrict__ be2, float* __restrict__ out0) {
    __shared__ float sW1T[HID * LOOKBACK];   // [h][l]
    __shared__ float sB1[HID];
    __shared__ float sW2[HID];
    for (int e = threadIdx.x; e < HID * LOOKBACK; e += 256) {
        int l = e / HID, h = e % HID;
        sW1T[h * LOOKBACK + l] = We1[e];
    }
    for (int e = threadIdx.x; e < HID; e += 256) { sB1[e] = be1[e]; sW2[e] = We2[e]; }
    __syncthreads();
    int gid = blockIdx.x * 256 + threadIdx.x;
    if (gid >= N_NODES * FEAT) return;
    float xv[LOOKBACK];
    #pragma unroll
    for (int l = 0; l < LOOKBACK; ++l) xv[l] = x[(long)l * N_NODES * FEAT + gid];
    float acc = be2[0];
    for (int h = 0; h < HID; ++h) {
        float s = sB1[h];
        #pragma unroll
        for (int l = 0; l < LOOKBACK; ++l) s += xv[l] * sW1T[h * LOOKBACK + l];
        acc += fmaxf(s, 0.0f) * sW2[h];
    }
    out0[gid] = acc;
}

// ---------------- neighbor mean-gather + concat: cat = [aggr(h) | h] ----------------
template<int F, int NPB>
__global__ __launch_bounds__(256)
void gather_kernel(const float* __restrict__ h, const int* __restrict__ lists,
                   const int* __restrict__ cnt, const float* __restrict__ degf,
                   float* __restrict__ cat) {
    const int TPN = 256 / NPB;               // TPN*8 == F
    int ln  = threadIdx.x / TPN;
    int sub = threadIdx.x % TPN;
    int n = blockIdx.x * NPB + ln;
    if (n >= N_NODES) return;
    int f0 = sub * 8;
    float acc[8] = {0, 0, 0, 0, 0, 0, 0, 0};
    int m = cnt[n];
    const int* l = lists + (long)n * CAP;
    for (int e = 0; e < m; ++e) {
        int i = l[e];
        const float* hp = h + (long)i * F + f0;
        float4 a = *reinterpret_cast<const float4*>(hp);
        float4 b = *reinterpret_cast<const float4*>(hp + 4);
        acc[0] += a.x; acc[1] += a.y; acc[2] += a.z; acc[3] += a.w;
        acc[4] += b.x; acc[5] += b.y; acc[6] += b.z; acc[7] += b.w;
    }
    float inv = 1.0f / degf[n];
    float* cp = cat + (long)n * (2 * F);
    const float* hn = h + (long)n * F + f0;
    #pragma unroll
    for (int c = 0; c < 8; ++c) cp[f0 + c] = acc[c] * inv;
    #pragma unroll
    for (int c = 0; c < 8; ++c) cp[F + f0 + c] = hn[c];
}

// ---------------- generic GEMV-ish GEMM: out[n,j] = act(bias[j] + in[n,:]@W[:,j]) ----------------
template<int K, int J, bool RELU, bool FINAL>
__global__ __launch_bounds__(256)
void gemm_kernel(const float* __restrict__ in, const float* __restrict__ W,
                 const float* __restrict__ bias, float* __restrict__ out,
                 const float* __restrict__ xs, const float* __restrict__ hcur,
                 const float* __restrict__ tspan, int step) {
    long t = (long)blockIdx.x * 256 + threadIdx.x;
    if (t >= (long)N_NODES * J) return;
    int n = (int)(t / J);
    int j = (int)(t % J);
    const float* ip = in + (long)n * K;
    float acc = bias[j];
    #pragma unroll 4
    for (int k = 0; k < K; ++k) acc += ip[k] * W[(long)k * J + j];
    if (RELU) acc = fmaxf(acc, 0.0f);
    if (FINAL) {
        float dt = tspan[step + 1] - tspan[step];
        float s = xs[t] + acc;                       // x_self + x_neigh
        s = fminf(fmaxf(s, -1000.0f), 1000.0f);      // clip
        acc = hcur[t] + dt * s;                      // Euler step
    }
    out[t] = acc;
}

extern "C" void kernel_launch(void* const* d_in, const int* in_sizes, int n_in,
                              void* d_out, int out_size, void* d_ws, size_t ws_size,
                              hipStream_t stream) {
    const float* tspan = (const float*)d_in[0];
    const float* x     = (const float*)d_in[1];
    const float* adj   = (const float*)d_in[2];
    const float* We1   = (const float*)d_in[3];
    const float* be1   = (const float*)d_in[4];
    const float* We2   = (const float*)d_in[5];
    const float* be2   = (const float*)d_in[6];
    const float* Wf1   = (const float*)d_in[7];
    const float* bf1   = (const float*)d_in[8];
    const float* Wf2   = (const float*)d_in[9];
    const float* bf2   = (const float*)d_in[10];
    const float* Wl1   = (const float*)d_in[11];
    const float* bl1   = (const float*)d_in[12];
    const float* Wr1   = (const float*)d_in[13];
    const float* Wl2   = (const float*)d_in[14];
    const float* bl2   = (const float*)d_in[15];
    const float* Wr2   = (const float*)d_in[16];
    float* out = (float*)d_out;

    // workspace layout (bytes)
    char* ws = (char*)d_ws;
    int*   lists = (int*)  (ws + 0);          // 8000*64*4      = 2,048,000
    int*   cnt   = (int*)  (ws + 2048000);    // 8000*4
    float* degf  = (float*)(ws + 2080000);    // 8000*4
    float* Ws1   = (float*)(ws + 2112000);    // 128*128*4      = 65,536
    float* Ws2   = (float*)(ws + 2177536);    // 256*64*4       = 65,536
    float* cat1  = (float*)(ws + 2243072);    // 8000*128*4     = 4,096,000
    float* cat2  = (float*)(ws + 6339072);    // 8000*256*4     = 8,192,000
    float* t1    = (float*)(ws + 14531072);   // 8000*128*4     = 4,096,000
    float* r1    = (float*)(ws + 18627072);   // 8000*128*4     = 4,096,000
    float* xsb   = (float*)(ws + 22723072);   // 8000*64*4      = 2,048,000
    // total = 24,771,072 bytes

    hipMemsetAsync(cnt, 0, N_NODES * sizeof(int), stream);
    build_adj_kernel<<<62500, 256, 0, stream>>>(adj, cnt, lists);
    sort_deg_kernel<<<(N_NODES + 255) / 256, 256, 0, stream>>>(cnt, lists, degf);
    prep_weights_kernel<<<128, 256, 0, stream>>>(Wl1, Wr1, Wl2, Wr2, Ws1, Ws2);
    init_enc_kernel<<<2000, 256, 0, stream>>>(x, We1, be1, We2, be2, out);

    for (int s = 0; s < 3; ++s) {
        const float* hcur  = out + (long)s       * N_NODES * FEAT;
        float*       hnext = out + (long)(s + 1) * N_NODES * FEAT;
        // SAGE1: cat1 = [mean-aggr(hcur) | hcur];  r1 = relu(cat1 @ [Wl1;Wr1] + bl1)
        gather_kernel<64, 32><<<250, 256, 0, stream>>>(hcur, lists, cnt, degf, cat1);
        gemm_kernel<128, 128, true, false><<<4000, 256, 0, stream>>>(
            cat1, Ws1, bl1, r1, nullptr, nullptr, nullptr, 0);
        // self-MLP: t1 = relu(hcur @ Wf1 + bf1);  xs = t1 @ Wf2 + bf2
        gemm_kernel<64, 128, true, false><<<4000, 256, 0, stream>>>(
            hcur, Wf1, bf1, t1, nullptr, nullptr, nullptr, 0);
        gemm_kernel<128, 64, false, false><<<2000, 256, 0, stream>>>(
            t1, Wf2, bf2, xsb, nullptr, nullptr, nullptr, 0);
        // SAGE2 + epilogue: hnext = hcur + dt * clip(xs + cat2 @ [Wl2;Wr2] + bl2)
        gather_kernel<128, 16><<<500, 256, 0, stream>>>(r1, lists, cnt, degf, cat2);
        gemm_kernel<256, 64, false, true><<<2000, 256, 0, stream>>>(
            cat2, Ws2, bl2, hnext, xsb, hcur, tspan, s);
    }
}

// Round 2
// 367.964 us; speedup vs baseline: 1.4155x; 1.4155x over previous
//
#include <hip/hip_runtime.h>

#define N_NODES 8000
#define FEAT 64
#define HID 128
#define LOOKBACK 12
#define CAP 64

// ---------------- adjacency pattern extraction ----------------
__global__ __launch_bounds__(256)
void build_adj_kernel(const float* __restrict__ adj, int* __restrict__ cnt,
                      int* __restrict__ lists) {
    long q = (long)blockIdx.x * 256 + threadIdx.x;           // float4 index
    const long NQ = (long)N_NODES * N_NODES / 4;
    if (q >= NQ) return;
    int i  = (int)(q / (N_NODES / 4));
    int j0 = (int)(q % (N_NODES / 4)) * 4;
    float4 w = *reinterpret_cast<const float4*>(adj + (long)i * N_NODES + j0);
    float wv[4] = {w.x, w.y, w.z, w.w};
    #pragma unroll
    for (int c = 0; c < 4; ++c) {
        if (wv[c] != 0.0f) {
            int j = j0 + c;
            int p = atomicAdd(&cnt[j], 1);
            if (p < CAP) lists[(long)j * CAP + p] = i;       // edge i -> j
        }
    }
}

// sort lists (determinism) + deg + stack weights, one kernel
// threads [0,8000): sort+deg; [8192,8192+16384): Ws1; [+16384,+32768): Wc2
__global__ __launch_bounds__(256)
void prep_kernel(int* __restrict__ cnt, int* __restrict__ lists,
                 float* __restrict__ degf,
                 const float* __restrict__ Wl1, const float* __restrict__ Wr1,
                 const float* __restrict__ Wl2, const float* __restrict__ Wr2,
                 float* __restrict__ Ws1, float* __restrict__ Wc2) {
    int g = blockIdx.x * 256 + threadIdx.x;
    if (g < N_NODES) {
        int m = cnt[g];
        if (m > CAP) m = CAP;
        cnt[g] = m;
        int* l = lists + (long)g * CAP;
        for (int a = 1; a < m; ++a) {
            int v = l[a];
            int b = a - 1;
            while (b >= 0 && l[b] > v) { l[b + 1] = l[b]; --b; }
            l[b + 1] = v;
        }
        degf[g] = (float)(m > 0 ? m : 1);
    } else if (g >= 8192) {
        int u = g - 8192;
        if (u < 128 * 128) {            // Ws1[k][j] = [Wl1;Wr1]
            int k = u >> 7, j = u & 127;
            Ws1[u] = (k < 64) ? Wl1[k * 128 + j] : Wr1[(k - 64) * 128 + j];
        } else if (u < 2 * 128 * 128) { // Wc2[k][j] = [Wl2 | Wr2] (col-stacked)
            int w = u - 128 * 128;
            int k = w >> 7, j = w & 127;
            Wc2[w] = (j < 64) ? Wl2[k * 64 + j] : Wr2[k * 64 + (j - 64)];
        }
    }
}

// ---------------- init encoder: x[L,N,F] -> x0[N,F], 4 elems/thread ----------------
__global__ __launch_bounds__(256)
void init_enc_kernel(const float* __restrict__ x, const float* __restrict__ We1,
                     const float* __restrict__ be1, const float* __restrict__ We2,
                     const float* __restrict__ be2, float* __restrict__ out0) {
    __shared__ float sW1T[HID * LOOKBACK];   // [h][l]
    __shared__ float sB1[HID];
    __shared__ float sW2[HID];
    for (int e = threadIdx.x; e < HID * LOOKBACK; e += 256) {
        int l = e / HID, h = e % HID;
        sW1T[h * LOOKBACK + l] = We1[e];
    }
    for (int e = threadIdx.x; e < HID; e += 256) { sB1[e] = be1[e]; sW2[e] = We2[e]; }
    __syncthreads();
    int g = (blockIdx.x * 256 + threadIdx.x) * 4;            // 4 consecutive (n,f) elems
    if (g >= N_NODES * FEAT) return;
    float xv[4][LOOKBACK];
    #pragma unroll
    for (int l = 0; l < LOOKBACK; ++l) {
        float4 v = *reinterpret_cast<const float4*>(x + (long)l * N_NODES * FEAT + g);
        xv[0][l] = v.x; xv[1][l] = v.y; xv[2][l] = v.z; xv[3][l] = v.w;
    }
    float b2 = be2[0];
    float acc[4] = {b2, b2, b2, b2};
    for (int h = 0; h < HID; ++h) {
        float s0 = sB1[h], s1 = s0, s2 = s0, s3 = s0;
        #pragma unroll
        for (int l = 0; l < LOOKBACK; ++l) {
            float w = sW1T[h * LOOKBACK + l];
            s0 += xv[0][l] * w; s1 += xv[1][l] * w;
            s2 += xv[2][l] * w; s3 += xv[3][l] * w;
        }
        float w2 = sW2[h];
        acc[0] += fmaxf(s0, 0.0f) * w2; acc[1] += fmaxf(s1, 0.0f) * w2;
        acc[2] += fmaxf(s2, 0.0f) * w2; acc[3] += fmaxf(s3, 0.0f) * w2;
    }
    float4 o = {acc[0], acc[1], acc[2], acc[3]};
    *reinterpret_cast<float4*>(out0 + g) = o;
}

// ---------------- SAGE1 fused: r1 = relu(bl1 + mean(h_nbr)@Wl1 + h@Wr1) ----------------
// 16 nodes/block, 16 threads/node, 8 output cols/thread
__global__ __launch_bounds__(256)
void sage1_kernel(const float* __restrict__ h, const int* __restrict__ lists,
                  const int* __restrict__ cnt, const float* __restrict__ degf,
                  const float* __restrict__ Ws1, const float* __restrict__ bl1,
                  float* __restrict__ r1) {
    __shared__ float v[16][132];             // [node][k]: k<64 aggr, k>=64 h row
    int tid = threadIdx.x;
    int ln = tid >> 4, jg = tid & 15;
    int n = blockIdx.x * 16 + ln;
    int f0 = jg * 4;
    {   // gather mean: this thread handles 4 feats for node n
        int m = cnt[n];
        const int* l = lists + (long)n * CAP;
        float inv = 1.0f / degf[n];
        float4 a = {0, 0, 0, 0};
        for (int e = 0; e < m; ++e) {
            int i = l[e];
            float4 b = *reinterpret_cast<const float4*>(h + (long)i * FEAT + f0);
            a.x += b.x; a.y += b.y; a.z += b.z; a.w += b.w;
        }
        v[ln][f0 + 0] = a.x * inv; v[ln][f0 + 1] = a.y * inv;
        v[ln][f0 + 2] = a.z * inv; v[ln][f0 + 3] = a.w * inv;
        float4 hv = *reinterpret_cast<const float4*>(h + (long)n * FEAT + f0);
        v[ln][64 + f0 + 0] = hv.x; v[ln][64 + f0 + 1] = hv.y;
        v[ln][64 + f0 + 2] = hv.z; v[ln][64 + f0 + 3] = hv.w;
    }
    __syncthreads();
    int j0 = jg * 8;
    float acc[8];
    #pragma unroll
    for (int c = 0; c < 8; ++c) acc[c] = bl1[j0 + c];
    #pragma unroll 4
    for (int k = 0; k < 128; ++k) {
        float vv = v[ln][k];
        float4 w0 = *reinterpret_cast<const float4*>(Ws1 + k * 128 + j0);
        float4 w1 = *reinterpret_cast<const float4*>(Ws1 + k * 128 + j0 + 4);
        acc[0] += vv * w0.x; acc[1] += vv * w0.y; acc[2] += vv * w0.z; acc[3] += vv * w0.w;
        acc[4] += vv * w1.x; acc[5] += vv * w1.y; acc[6] += vv * w1.z; acc[7] += vv * w1.w;
    }
    float4 o0 = {fmaxf(acc[0], 0.f), fmaxf(acc[1], 0.f), fmaxf(acc[2], 0.f), fmaxf(acc[3], 0.f)};
    float4 o1 = {fmaxf(acc[4], 0.f), fmaxf(acc[5], 0.f), fmaxf(acc[6], 0.f), fmaxf(acc[7], 0.f)};
    *reinterpret_cast<float4*>(r1 + (long)n * HID + j0)     = o0;
    *reinterpret_cast<float4*>(r1 + (long)n * HID + j0 + 4) = o1;
}

// ---------------- proj+self fused ----------------
// pl = r1 @ Wl2 ;  q = r1 @ Wr2 + bl2 + selfMLP(h)
__global__ __launch_bounds__(256)
void proj_kernel(const float* __restrict__ h, const float* __restrict__ r1,
                 const float* __restrict__ Wc2, const float* __restrict__ bl2,
                 const float* __restrict__ Wf1, const float* __restrict__ bf1,
                 const float* __restrict__ Wf2, const float* __restrict__ bf2,
                 float* __restrict__ pl, float* __restrict__ q) {
    __shared__ float rL[16][132];            // r1 rows
    __shared__ float hL[16][68];             // h rows
    __shared__ float tL[16][132];            // hidden relu
    __shared__ float xsL[16][68];            // x_self
    int tid = threadIdx.x;
    int ln = tid >> 4, jg = tid & 15;
    int n = blockIdx.x * 16 + ln;
    int j0 = jg * 8;
    {   // stage r1 row (8 floats) + h row (4 floats)
        float4 ra = *reinterpret_cast<const float4*>(r1 + (long)n * HID + j0);
        float4 rb = *reinterpret_cast<const float4*>(r1 + (long)n * HID + j0 + 4);
        rL[ln][j0 + 0] = ra.x; rL[ln][j0 + 1] = ra.y; rL[ln][j0 + 2] = ra.z; rL[ln][j0 + 3] = ra.w;
        rL[ln][j0 + 4] = rb.x; rL[ln][j0 + 5] = rb.y; rL[ln][j0 + 6] = rb.z; rL[ln][j0 + 7] = rb.w;
        float4 hv = *reinterpret_cast<const float4*>(h + (long)n * FEAT + jg * 4);
        hL[ln][jg * 4 + 0] = hv.x; hL[ln][jg * 4 + 1] = hv.y;
        hL[ln][jg * 4 + 2] = hv.z; hL[ln][jg * 4 + 3] = hv.w;
    }
    __syncthreads();
    // hidden: t = relu(h @ Wf1 + bf1), cols j0..j0+7
    float th[8];
    #pragma unroll
    for (int c = 0; c < 8; ++c) th[c] = bf1[j0 + c];
    #pragma unroll 4
    for (int k = 0; k < 64; ++k) {
        float vv = hL[ln][k];
        float4 w0 = *reinterpret_cast<const float4*>(Wf1 + k * 128 + j0);
        float4 w1 = *reinterpret_cast<const float4*>(Wf1 + k * 128 + j0 + 4);
        th[0] += vv * w0.x; th[1] += vv * w0.y; th[2] += vv * w0.z; th[3] += vv * w0.w;
        th[4] += vv * w1.x; th[5] += vv * w1.y; th[6] += vv * w1.z; th[7] += vv * w1.w;
    }
    #pragma unroll
    for (int c = 0; c < 8; ++c) tL[ln][j0 + c] = fmaxf(th[c], 0.0f);
    // P = r1 @ Wc2, cols j0..j0+7 (independent of tL barrier)
    float pa[8];
    #pragma unroll
    for (int c = 0; c < 8; ++c) pa[c] = 0.0f;
    #pragma unroll 4
    for (int k = 0; k < 128; ++k) {
        float vv = rL[ln][k];
        float4 w0 = *reinterpret_cast<const float4*>(Wc2 + k * 128 + j0);
        float4 w1 = *reinterpret_cast<const float4*>(Wc2 + k * 128 + j0 + 4);
        pa[0] += vv * w0.x; pa[1] += vv * w0.y; pa[2] += vv * w0.z; pa[3] += vv * w0.w;
        pa[4] += vv * w1.x; pa[5] += vv * w1.y; pa[6] += vv * w1.z; pa[7] += vv * w1.w;
    }
    __syncthreads();                          // tL ready
    if (jg < 8) {
        // pl cols j0..j0+7
        float4 o0 = {pa[0], pa[1], pa[2], pa[3]};
        float4 o1 = {pa[4], pa[5], pa[6], pa[7]};
        *reinterpret_cast<float4*>(pl + (long)n * FEAT + j0)     = o0;
        *reinterpret_cast<float4*>(pl + (long)n * FEAT + j0 + 4) = o1;
        // xs cols j0..j0+7
        float xa[8];
        #pragma unroll
        for (int c = 0; c < 8; ++c) xa[c] = bf2[j0 + c];
        #pragma unroll 4
        for (int k = 0; k < 128; ++k) {
            float vv = tL[ln][k];
            float4 w0 = *reinterpret_cast<const float4*>(Wf2 + k * 64 + j0);
            float4 w1 = *reinterpret_cast<const float4*>(Wf2 + k * 64 + j0 + 4);
            xa[0] += vv * w0.x; xa[1] += vv * w0.y; xa[2] += vv * w0.z; xa[3] += vv * w0.w;
            xa[4] += vv * w1.x; xa[5] += vv * w1.y; xa[6] += vv * w1.z; xa[7] += vv * w1.w;
        }
        #pragma unroll
        for (int c = 0; c < 8; ++c) xsL[ln][j0 + c] = xa[c];
    }
    __syncthreads();                          // xsL ready
    if (jg >= 8) {
        int c0 = (jg - 8) * 8;                // pr cols c0..c0+7
        float4 o0, o1;
        o0.x = pa[0] + xsL[ln][c0 + 0] + bl2[c0 + 0];
        o0.y = pa[1] + xsL[ln][c0 + 1] + bl2[c0 + 1];
        o0.z = pa[2] + xsL[ln][c0 + 2] + bl2[c0 + 2];
        o0.w = pa[3] + xsL[ln][c0 + 3] + bl2[c0 + 3];
        o1.x = pa[4] + xsL[ln][c0 + 4] + bl2[c0 + 4];
        o1.y = pa[5] + xsL[ln][c0 + 5] + bl2[c0 + 5];
        o1.z = pa[6] + xsL[ln][c0 + 6] + bl2[c0 + 6];
        o1.w = pa[7] + xsL[ln][c0 + 7] + bl2[c0 + 7];
        *reinterpret_cast<float4*>(q + (long)n * FEAT + c0)     = o0;
        *reinterpret_cast<float4*>(q + (long)n * FEAT + c0 + 4) = o1;
    }
}

// ---------------- gather + Euler epilogue ----------------
// hnext = hcur + dt * clip(q + mean(pl_nbr), +-1000)
__global__ __launch_bounds__(256)
void epi_kernel(const float* __restrict__ pl, const float* __restrict__ q,
                const int* __restrict__ lists, const int* __restrict__ cnt,
                const float* __restrict__ degf, const float* __restrict__ hcur,
                const float* __restrict__ tspan, int step,
                float* __restrict__ hnext) {
    int tid = threadIdx.x;
    int ln = tid >> 4, sub = tid & 15;
    int n = blockIdx.x * 16 + ln;
    int f0 = sub * 4;
    int m = cnt[n];
    const int* l = lists + (long)n * CAP;
    float inv = 1.0f / degf[n];
    float4 a = {0, 0, 0, 0};
    for (int e = 0; e < m; ++e) {
        int i = l[e];
        float4 b = *reinterpret_cast<const float4*>(pl + (long)i * FEAT + f0);
        a.x += b.x; a.y += b.y; a.z += b.z; a.w += b.w;
    }
    float dt = tspan[step + 1] - tspan[step];
    float4 qv = *reinterpret_cast<const float4*>(q + (long)n * FEAT + f0);
    float4 hv = *reinterpret_cast<const float4*>(hcur + (long)n * FEAT + f0);
    float s0 = qv.x + a.x * inv, s1 = qv.y + a.y * inv;
    float s2 = qv.z + a.z * inv, s3 = qv.w + a.w * inv;
    s0 = fminf(fmaxf(s0, -1000.f), 1000.f); s1 = fminf(fmaxf(s1, -1000.f), 1000.f);
    s2 = fminf(fmaxf(s2, -1000.f), 1000.f); s3 = fminf(fmaxf(s3, -1000.f), 1000.f);
    float4 o = {hv.x + dt * s0, hv.y + dt * s1, hv.z + dt * s2, hv.w + dt * s3};
    *reinterpret_cast<float4*>(hnext + (long)n * FEAT + f0) = o;
}

extern "C" void kernel_launch(void* const* d_in, const int* in_sizes, int n_in,
                              void* d_out, int out_size, void* d_ws, size_t ws_size,
                              hipStream_t stream) {
    const float* tspan = (const float*)d_in[0];
    const float* x     = (const float*)d_in[1];
    const float* adj   = (const float*)d_in[2];
    const float* We1   = (const float*)d_in[3];
    const float* be1   = (const float*)d_in[4];
    const float* We2   = (const float*)d_in[5];
    const float* be2   = (const float*)d_in[6];
    const float* Wf1   = (const float*)d_in[7];
    const float* bf1   = (const float*)d_in[8];
    const float* Wf2   = (const float*)d_in[9];
    const float* bf2   = (const float*)d_in[10];
    const float* Wl1   = (const float*)d_in[11];
    const float* bl1   = (const float*)d_in[12];
    const float* Wr1   = (const float*)d_in[13];
    const float* Wl2   = (const float*)d_in[14];
    const float* bl2   = (const float*)d_in[15];
    const float* Wr2   = (const float*)d_in[16];
    float* out = (float*)d_out;

    // workspace layout (bytes)
    char* ws = (char*)d_ws;
    int*   lists = (int*)  (ws + 0);           // 8000*64*4  = 2,048,000
    int*   cnt   = (int*)  (ws + 2048000);     // 32,000
    float* degf  = (float*)(ws + 2080000);     // 32,000
    float* Ws1   = (float*)(ws + 2112000);     // 65,536
    float* Wc2   = (float*)(ws + 2177536);     // 65,536
    float* r1    = (float*)(ws + 2243072);     // 8000*128*4 = 4,096,000
    float* pl    = (float*)(ws + 6339072);     // 8000*64*4  = 2,048,000
    float* q     = (float*)(ws + 8387072);     // 8000*64*4  = 2,048,000
    // total 10,435,072 bytes

    hipMemsetAsync(cnt, 0, N_NODES * sizeof(int), stream);
    build_adj_kernel<<<62500, 256, 0, stream>>>(adj, cnt, lists);
    prep_kernel<<<160, 256, 0, stream>>>(cnt, lists, degf, Wl1, Wr1, Wl2, Wr2, Ws1, Wc2);
    init_enc_kernel<<<500, 256, 0, stream>>>(x, We1, be1, We2, be2, out);

    for (int s = 0; s < 3; ++s) {
        const float* hcur  = out + (long)s       * N_NODES * FEAT;
        float*       hnext = out + (long)(s + 1) * N_NODES * FEAT;
        sage1_kernel<<<500, 256, 0, stream>>>(hcur, lists, cnt, degf, Ws1, bl1, r1);
        proj_kernel<<<500, 256, 0, stream>>>(hcur, r1, Wc2, bl2, Wf1, bf1, Wf2, bf2, pl, q);
        epi_kernel<<<500, 256, 0, stream>>>(pl, q, lists, cnt, degf, hcur, tspan, s, hnext);
    }
}

// Round 3
// 313.282 us; speedup vs baseline: 1.6626x; 1.1745x over previous
//
#include <hip/hip_runtime.h>

#define N_NODES 8000
#define FEAT 64
#define HID 128
#define LOOKBACK 12
#define CAP 64

// ---------------- adjacency pattern extraction ----------------
__global__ __launch_bounds__(256)
void build_adj_kernel(const float* __restrict__ adj, int* __restrict__ cnt,
                      int* __restrict__ lists) {
    long q = (long)blockIdx.x * 256 + threadIdx.x;           // float4 index
    const long NQ = (long)N_NODES * N_NODES / 4;
    if (q >= NQ) return;
    int i  = (int)(q / (N_NODES / 4));
    int j0 = (int)(q % (N_NODES / 4)) * 4;
    float4 w = *reinterpret_cast<const float4*>(adj + (long)i * N_NODES + j0);
    float wv[4] = {w.x, w.y, w.z, w.w};
    #pragma unroll
    for (int c = 0; c < 4; ++c) {
        if (wv[c] != 0.0f) {
            int j = j0 + c;
            int p = atomicAdd(&cnt[j], 1);
            if (p < CAP) lists[(long)j * CAP + p] = i;       // edge i -> j
        }
    }
}

// sort lists (determinism) + deg + stack weights, one kernel
__global__ __launch_bounds__(256)
void prep_kernel(int* __restrict__ cnt, int* __restrict__ lists,
                 float* __restrict__ degf,
                 const float* __restrict__ Wl1, const float* __restrict__ Wr1,
                 const float* __restrict__ Wl2, const float* __restrict__ Wr2,
                 float* __restrict__ Ws1, float* __restrict__ Wc2) {
    int g = blockIdx.x * 256 + threadIdx.x;
    if (g < N_NODES) {
        int m = cnt[g];
        if (m > CAP) m = CAP;
        cnt[g] = m;
        int* l = lists + (long)g * CAP;
        for (int a = 1; a < m; ++a) {
            int v = l[a];
            int b = a - 1;
            while (b >= 0 && l[b] > v) { l[b + 1] = l[b]; --b; }
            l[b + 1] = v;
        }
        degf[g] = (float)(m > 0 ? m : 1);
    } else if (g >= 8192) {
        int u = g - 8192;
        if (u < 128 * 128) {            // Ws1[k][j] = [Wl1;Wr1] row-stacked
            int k = u >> 7, j = u & 127;
            Ws1[u] = (k < 64) ? Wl1[k * 128 + j] : Wr1[(k - 64) * 128 + j];
        } else if (u < 2 * 128 * 128) { // Wc2[k][j] = [Wl2 | Wr2] col-stacked
            int w = u - 128 * 128;
            int k = w >> 7, j = w & 127;
            Wc2[w] = (j < 64) ? Wl2[k * 64 + j] : Wr2[k * 64 + (j - 64)];
        }
    }
}

// ---------------- init encoder: x[L,N,F] -> x0[N,F], 4 elems/thread ----------------
__global__ __launch_bounds__(256)
void init_enc_kernel(const float* __restrict__ x, const float* __restrict__ We1,
                     const float* __restrict__ be1, const float* __restrict__ We2,
                     const float* __restrict__ be2, float* __restrict__ out0) {
    __shared__ float sW1T[HID * LOOKBACK];   // [h][l]
    __shared__ float sB1[HID];
    __shared__ float sW2[HID];
    for (int e = threadIdx.x; e < HID * LOOKBACK; e += 256) {
        int l = e / HID, h = e % HID;
        sW1T[h * LOOKBACK + l] = We1[e];
    }
    for (int e = threadIdx.x; e < HID; e += 256) { sB1[e] = be1[e]; sW2[e] = We2[e]; }
    __syncthreads();
    int g = (blockIdx.x * 256 + threadIdx.x) * 4;
    if (g >= N_NODES * FEAT) return;
    float xv[4][LOOKBACK];
    #pragma unroll
    for (int l = 0; l < LOOKBACK; ++l) {
        float4 v = *reinterpret_cast<const float4*>(x + (long)l * N_NODES * FEAT + g);
        xv[0][l] = v.x; xv[1][l] = v.y; xv[2][l] = v.z; xv[3][l] = v.w;
    }
    float b2 = be2[0];
    float acc[4] = {b2, b2, b2, b2};
    for (int h = 0; h < HID; ++h) {
        float s0 = sB1[h], s1 = s0, s2 = s0, s3 = s0;
        #pragma unroll
        for (int l = 0; l < LOOKBACK; ++l) {
            float w = sW1T[h * LOOKBACK + l];
            s0 += xv[0][l] * w; s1 += xv[1][l] * w;
            s2 += xv[2][l] * w; s3 += xv[3][l] * w;
        }
        float w2 = sW2[h];
        acc[0] += fmaxf(s0, 0.0f) * w2; acc[1] += fmaxf(s1, 0.0f) * w2;
        acc[2] += fmaxf(s2, 0.0f) * w2; acc[3] += fmaxf(s3, 0.0f) * w2;
    }
    float4 o = {acc[0], acc[1], acc[2], acc[3]};
    *reinterpret_cast<float4*>(out0 + g) = o;
}

// ---------------- fused SAGE1 + proj + selfMLP ----------------
// per node: r1 = relu([aggr(h)|h] @ Ws1 + bl1)   (kept in LDS)
//           t  = relu(h @ Wf1 + bf1)             (kept in LDS)
//           xs = t @ Wf2 + bf2                   (kept in LDS)
//           pl = r1 @ Wl2 ; q = r1 @ Wr2 + bl2 + xs
// 32 nodes/block, 250 blocks; GEMM phases: 16 col-groups x 16 lane-groups,
// each thread handles 2 nodes (lg, lg+16) per weight load.
__global__ __launch_bounds__(256)
void sageproj_kernel(const float* __restrict__ h, const int* __restrict__ lists,
                     const int* __restrict__ cnt, const float* __restrict__ degf,
                     const float* __restrict__ Ws1, const float* __restrict__ bl1,
                     const float* __restrict__ Wc2, const float* __restrict__ bl2,
                     const float* __restrict__ Wf1, const float* __restrict__ bf1,
                     const float* __restrict__ Wf2, const float* __restrict__ bf2,
                     float* __restrict__ pl, float* __restrict__ q) {
    __shared__ float v[32][132];     // [node][k]: k<64 aggr, k>=64 h row
    __shared__ float rr[32][132];    // r1
    __shared__ float tt[32][132];    // t = relu(h@Wf1+bf1)
    __shared__ float xsL[32][68];    // xs
    const int tid = threadIdx.x;
    const int nb = blockIdx.x * 32;
    {   // gather: 8 threads/node, 8 feats each
        const int ln = tid >> 3, sub = tid & 7;
        const int n = nb + ln;
        const int f0 = sub * 8;
        const int m = cnt[n];
        const int* l = lists + (long)n * CAP;
        const float inv = 1.0f / degf[n];
        float acc[8] = {0, 0, 0, 0, 0, 0, 0, 0};
        for (int e = 0; e < m; ++e) {
            const float* hp = h + (long)l[e] * FEAT + f0;
            float4 b0 = *reinterpret_cast<const float4*>(hp);
            float4 b1 = *reinterpret_cast<const float4*>(hp + 4);
            acc[0] += b0.x; acc[1] += b0.y; acc[2] += b0.z; acc[3] += b0.w;
            acc[4] += b1.x; acc[5] += b1.y; acc[6] += b1.z; acc[7] += b1.w;
        }
        float4 a0 = {acc[0] * inv, acc[1] * inv, acc[2] * inv, acc[3] * inv};
        float4 a1 = {acc[4] * inv, acc[5] * inv, acc[6] * inv, acc[7] * inv};
        *reinterpret_cast<float4*>(&v[ln][f0])     = a0;
        *reinterpret_cast<float4*>(&v[ln][f0 + 4]) = a1;
        const float* hn = h + (long)n * FEAT + f0;
        *reinterpret_cast<float4*>(&v[ln][64 + f0])     = *reinterpret_cast<const float4*>(hn);
        *reinterpret_cast<float4*>(&v[ln][64 + f0 + 4]) = *reinterpret_cast<const float4*>(hn + 4);
    }
    __syncthreads();
    const int jg = tid & 15, lg = tid >> 4;
    const int j0 = jg * 8;
    // P1: r1 (K=128)
    {
        float A0[8], A1[8];
        #pragma unroll
        for (int c = 0; c < 8; ++c) { A0[c] = bl1[j0 + c]; A1[c] = A0[c]; }
        #pragma unroll 4
        for (int k = 0; k < 128; ++k) {
            float4 w0 = *reinterpret_cast<const float4*>(Ws1 + k * 128 + j0);
            float4 w1 = *reinterpret_cast<const float4*>(Ws1 + k * 128 + j0 + 4);
            float a = v[lg][k], b = v[lg + 16][k];
            A0[0] += a * w0.x; A0[1] += a * w0.y; A0[2] += a * w0.z; A0[3] += a * w0.w;
            A0[4] += a * w1.x; A0[5] += a * w1.y; A0[6] += a * w1.z; A0[7] += a * w1.w;
            A1[0] += b * w0.x; A1[1] += b * w0.y; A1[2] += b * w0.z; A1[3] += b * w0.w;
            A1[4] += b * w1.x; A1[5] += b * w1.y; A1[6] += b * w1.z; A1[7] += b * w1.w;
        }
        float4 o;
        o = {fmaxf(A0[0],0.f), fmaxf(A0[1],0.f), fmaxf(A0[2],0.f), fmaxf(A0[3],0.f)};
        *reinterpret_cast<float4*>(&rr[lg][j0]) = o;
        o = {fmaxf(A0[4],0.f), fmaxf(A0[5],0.f), fmaxf(A0[6],0.f), fmaxf(A0[7],0.f)};
        *reinterpret_cast<float4*>(&rr[lg][j0 + 4]) = o;
        o = {fmaxf(A1[0],0.f), fmaxf(A1[1],0.f), fmaxf(A1[2],0.f), fmaxf(A1[3],0.f)};
        *reinterpret_cast<float4*>(&rr[lg + 16][j0]) = o;
        o = {fmaxf(A1[4],0.f), fmaxf(A1[5],0.f), fmaxf(A1[6],0.f), fmaxf(A1[7],0.f)};
        *reinterpret_cast<float4*>(&rr[lg + 16][j0 + 4]) = o;
    }
    // P2: t (K=64, input = h part of v)
    {
        float A0[8], A1[8];
        #pragma unroll
        for (int c = 0; c < 8; ++c) { A0[c] = bf1[j0 + c]; A1[c] = A0[c]; }
        #pragma unroll 4
        for (int k = 0; k < 64; ++k) {
            float4 w0 = *reinterpret_cast<const float4*>(Wf1 + k * 128 + j0);
            float4 w1 = *reinterpret_cast<const float4*>(Wf1 + k * 128 + j0 + 4);
            float a = v[lg][64 + k], b = v[lg + 16][64 + k];
            A0[0] += a * w0.x; A0[1] += a * w0.y; A0[2] += a * w0.z; A0[3] += a * w0.w;
            A0[4] += a * w1.x; A0[5] += a * w1.y; A0[6] += a * w1.z; A0[7] += a * w1.w;
            A1[0] += b * w0.x; A1[1] += b * w0.y; A1[2] += b * w0.z; A1[3] += b * w0.w;
            A1[4] += b * w1.x; A1[5] += b * w1.y; A1[6] += b * w1.z; A1[7] += b * w1.w;
        }
        float4 o;
        o = {fmaxf(A0[0],0.f), fmaxf(A0[1],0.f), fmaxf(A0[2],0.f), fmaxf(A0[3],0.f)};
        *reinterpret_cast<float4*>(&tt[lg][j0]) = o;
        o = {fmaxf(A0[4],0.f), fmaxf(A0[5],0.f), fmaxf(A0[6],0.f), fmaxf(A0[7],0.f)};
        *reinterpret_cast<float4*>(&tt[lg][j0 + 4]) = o;
        o = {fmaxf(A1[0],0.f), fmaxf(A1[1],0.f), fmaxf(A1[2],0.f), fmaxf(A1[3],0.f)};
        *reinterpret_cast<float4*>(&tt[lg + 16][j0]) = o;
        o = {fmaxf(A1[4],0.f), fmaxf(A1[5],0.f), fmaxf(A1[6],0.f), fmaxf(A1[7],0.f)};
        *reinterpret_cast<float4*>(&tt[lg + 16][j0 + 4]) = o;
    }
    __syncthreads();
    // P3: xs = tt @ Wf2 + bf2 (64 cols, 4 cols/thread)
    {
        const int j4 = jg * 4;
        float X0[4], X1[4];
        #pragma unroll
        for (int c = 0; c < 4; ++c) { X0[c] = bf2[j4 + c]; X1[c] = X0[c]; }
        #pragma unroll 4
        for (int k = 0; k < 128; ++k) {
            float4 w = *reinterpret_cast<const float4*>(Wf2 + k * 64 + j4);
            float a = tt[lg][k], b = tt[lg + 16][k];
            X0[0] += a * w.x; X0[1] += a * w.y; X0[2] += a * w.z; X0[3] += a * w.w;
            X1[0] += b * w.x; X1[1] += b * w.y; X1[2] += b * w.z; X1[3] += b * w.w;
        }
        float4 o0 = {X0[0], X0[1], X0[2], X0[3]};
        float4 o1 = {X1[0], X1[1], X1[2], X1[3]};
        *reinterpret_cast<float4*>(&xsL[lg][j4])      = o0;
        *reinterpret_cast<float4*>(&xsL[lg + 16][j4]) = o1;
    }
    __syncthreads();
    // P4: [pl|q'] = rr @ Wc2 ; epilogue
    {
        float P0[8], P1v[8];
        #pragma unroll
        for (int c = 0; c < 8; ++c) { P0[c] = 0.0f; P1v[c] = 0.0f; }
        #pragma unroll 4
        for (int k = 0; k < 128; ++k) {
            float4 w0 = *reinterpret_cast<const float4*>(Wc2 + k * 128 + j0);
            float4 w1 = *reinterpret_cast<const float4*>(Wc2 + k * 128 + j0 + 4);
            float a = rr[lg][k], b = rr[lg + 16][k];
            P0[0] += a * w0.x; P0[1] += a * w0.y; P0[2] += a * w0.z; P0[3] += a * w0.w;
            P0[4] += a * w1.x; P0[5] += a * w1.y; P0[6] += a * w1.z; P0[7] += a * w1.w;
            P1v[0] += b * w0.x; P1v[1] += b * w0.y; P1v[2] += b * w0.z; P1v[3] += b * w0.w;
            P1v[4] += b * w1.x; P1v[5] += b * w1.y; P1v[6] += b * w1.z; P1v[7] += b * w1.w;
        }
        const int n0 = nb + lg, n1 = nb + lg + 16;
        if (jg < 8) {                                 // pl cols j0..j0+7
            float4 o;
            o = {P0[0], P0[1], P0[2], P0[3]};
            *reinterpret_cast<float4*>(pl + (long)n0 * FEAT + j0) = o;
            o = {P0[4], P0[5], P0[6], P0[7]};
            *reinterpret_cast<float4*>(pl + (long)n0 * FEAT + j0 + 4) = o;
            o = {P1v[0], P1v[1], P1v[2], P1v[3]};
            *reinterpret_cast<float4*>(pl + (long)n1 * FEAT + j0) = o;
            o = {P1v[4], P1v[5], P1v[6], P1v[7]};
            *reinterpret_cast<float4*>(pl + (long)n1 * FEAT + j0 + 4) = o;
        } else {                                      // q cols c0..c0+7
            const int c0 = j0 - 64;
            float4 o;
            o = {P0[0] + bl2[c0+0] + xsL[lg][c0+0], P0[1] + bl2[c0+1] + xsL[lg][c0+1],
                 P0[2] + bl2[c0+2] + xsL[lg][c0+2], P0[3] + bl2[c0+3] + xsL[lg][c0+3]};
            *reinterpret_cast<float4*>(q + (long)n0 * FEAT + c0) = o;
            o = {P0[4] + bl2[c0+4] + xsL[lg][c0+4], P0[5] + bl2[c0+5] + xsL[lg][c0+5],
                 P0[6] + bl2[c0+6] + xsL[lg][c0+6], P0[7] + bl2[c0+7] + xsL[lg][c0+7]};
            *reinterpret_cast<float4*>(q + (long)n0 * FEAT + c0 + 4) = o;
            o = {P1v[0] + bl2[c0+0] + xsL[lg+16][c0+0], P1v[1] + bl2[c0+1] + xsL[lg+16][c0+1],
                 P1v[2] + bl2[c0+2] + xsL[lg+16][c0+2], P1v[3] + bl2[c0+3] + xsL[lg+16][c0+3]};
            *reinterpret_cast<float4*>(q + (long)n1 * FEAT + c0) = o;
            o = {P1v[4] + bl2[c0+4] + xsL[lg+16][c0+4], P1v[5] + bl2[c0+5] + xsL[lg+16][c0+5],
                 P1v[6] + bl2[c0+6] + xsL[lg+16][c0+6], P1v[7] + bl2[c0+7] + xsL[lg+16][c0+7]};
            *reinterpret_cast<float4*>(q + (long)n1 * FEAT + c0 + 4) = o;
        }
    }
}

// ---------------- gather + Euler epilogue ----------------
// hnext = hcur + dt * clip(q + mean(pl_nbr), +-1000)
__global__ __launch_bounds__(256)
void epi_kernel(const float* __restrict__ pl, const float* __restrict__ q,
                const int* __restrict__ lists, const int* __restrict__ cnt,
                const float* __restrict__ degf, const float* __restrict__ hcur,
                const float* __restrict__ tspan, int step,
                float* __restrict__ hnext) {
    const int tid = threadIdx.x;
    const int ln = tid >> 3, sub = tid & 7;
    const int n = blockIdx.x * 32 + ln;
    const int f0 = sub * 8;
    const int m = cnt[n];
    const int* l = lists + (long)n * CAP;
    const float inv = 1.0f / degf[n];
    float acc[8] = {0, 0, 0, 0, 0, 0, 0, 0};
    for (int e = 0; e < m; ++e) {
        const float* pp = pl + (long)l[e] * FEAT + f0;
        float4 b0 = *reinterpret_cast<const float4*>(pp);
        float4 b1 = *reinterpret_cast<const float4*>(pp + 4);
        acc[0] += b0.x; acc[1] += b0.y; acc[2] += b0.z; acc[3] += b0.w;
        acc[4] += b1.x; acc[5] += b1.y; acc[6] += b1.z; acc[7] += b1.w;
    }
    const float dt = tspan[step + 1] - tspan[step];
    float4 q0 = *reinterpret_cast<const float4*>(q + (long)n * FEAT + f0);
    float4 q1 = *reinterpret_cast<const float4*>(q + (long)n * FEAT + f0 + 4);
    float4 h0 = *reinterpret_cast<const float4*>(hcur + (long)n * FEAT + f0);
    float4 h1 = *reinterpret_cast<const float4*>(hcur + (long)n * FEAT + f0 + 4);
    float qa[8] = {q0.x, q0.y, q0.z, q0.w, q1.x, q1.y, q1.z, q1.w};
    float ha[8] = {h0.x, h0.y, h0.z, h0.w, h1.x, h1.y, h1.z, h1.w};
    float oa[8];
    #pragma unroll
    for (int c = 0; c < 8; ++c) {
        float s = qa[c] + acc[c] * inv;
        s = fminf(fmaxf(s, -1000.0f), 1000.0f);
        oa[c] = ha[c] + dt * s;
    }
    float4 o0 = {oa[0], oa[1], oa[2], oa[3]};
    float4 o1 = {oa[4], oa[5], oa[6], oa[7]};
    *reinterpret_cast<float4*>(hnext + (long)n * FEAT + f0)     = o0;
    *reinterpret_cast<float4*>(hnext + (long)n * FEAT + f0 + 4) = o1;
}

extern "C" void kernel_launch(void* const* d_in, const int* in_sizes, int n_in,
                              void* d_out, int out_size, void* d_ws, size_t ws_size,
                              hipStream_t stream) {
    const float* tspan = (const float*)d_in[0];
    const float* x     = (const float*)d_in[1];
    const float* adj   = (const float*)d_in[2];
    const float* We1   = (const float*)d_in[3];
    const float* be1   = (const float*)d_in[4];
    const float* We2   = (const float*)d_in[5];
    const float* be2   = (const float*)d_in[6];
    const float* Wf1   = (const float*)d_in[7];
    const float* bf1   = (const float*)d_in[8];
    const float* Wf2   = (const float*)d_in[9];
    const float* bf2   = (const float*)d_in[10];
    const float* Wl1   = (const float*)d_in[11];
    const float* bl1   = (const float*)d_in[12];
    const float* Wr1   = (const float*)d_in[13];
    const float* Wl2   = (const float*)d_in[14];
    const float* bl2   = (const float*)d_in[15];
    const float* Wr2   = (const float*)d_in[16];
    float* out = (float*)d_out;

    // workspace layout (bytes)
    char* ws = (char*)d_ws;
    int*   lists = (int*)  (ws + 0);           // 8000*64*4  = 2,048,000
    int*   cnt   = (int*)  (ws + 2048000);     // 32,000
    float* degf  = (float*)(ws + 2080000);     // 32,000
    float* Ws1   = (float*)(ws + 2112000);     // 65,536
    float* Wc2   = (float*)(ws + 2177536);     // 65,536
    float* pl    = (float*)(ws + 2243072);     // 8000*64*4  = 2,048,000
    float* q     = (float*)(ws + 4291072);     // 8000*64*4  = 2,048,000
    // total 6,339,072 bytes

    hipMemsetAsync(cnt, 0, N_NODES * sizeof(int), stream);
    build_adj_kernel<<<62500, 256, 0, stream>>>(adj, cnt, lists);
    prep_kernel<<<160, 256, 0, stream>>>(cnt, lists, degf, Wl1, Wr1, Wl2, Wr2, Ws1, Wc2);
    init_enc_kernel<<<500, 256, 0, stream>>>(x, We1, be1, We2, be2, out);

    for (int s = 0; s < 3; ++s) {
        const float* hcur  = out + (long)s       * N_NODES * FEAT;
        float*       hnext = out + (long)(s + 1) * N_NODES * FEAT;
        sageproj_kernel<<<250, 256, 0, stream>>>(hcur, lists, cnt, degf,
                                                 Ws1, bl1, Wc2, bl2,
                                                 Wf1, bf1, Wf2, bf2, pl, q);
        epi_kernel<<<250, 256, 0, stream>>>(pl, q, lists, cnt, degf, hcur, tspan, s, hnext);
    }
}